// Round 5
// baseline (124.322 us; speedup 1.0000x reference)
//
#include <hip/hip_runtime.h>
#include <math.h>

#define BSZ 4096
#define NTOT 8192
#define DIM 128

typedef __attribute__((ext_vector_type(8))) short short8;   // 8 bf16 = 4 VGPR
typedef __attribute__((ext_vector_type(4))) float float4v;  // MFMA acc

constexpr float INV_T = 1.0f / 0.07f;
constexpr float M0    = INV_T;                 // row max of logits = diag = 1/T
constexpr float LOG2E = 1.4426950408889634f;
constexpr float K1    = INV_T * LOG2E;         // e^(s-M0) = 2^(c*K1 - K1)
constexpr float C3    = -0.5f * LOG2E;         // a = e^(-l^2/2) = 2^(l^2*C3)

__device__ __forceinline__ unsigned short f2bf(float x) {
    union { float f; unsigned u; } u; u.f = x;
    return (unsigned short)((u.u + 0x7FFFu + ((u.u >> 16) & 1)) >> 16);
}
__device__ __forceinline__ float bf2f(unsigned short s) {
    union { unsigned u; float f; } u; u.u = ((unsigned)s) << 16;
    return u.f;
}
__device__ __forceinline__ unsigned pack2(float a, float b) {
    return (unsigned)f2bf(a) | ((unsigned)f2bf(b) << 16);
}

// ---------- kernel A: fp32 normalize -> bf16 F[i][d], i = v*BSZ + b ----------
// 8 lanes per row, 16 floats per lane. grid 256 x 256thr = 8192 rows.
__global__ __launch_bounds__(256) void norm_k(const float* __restrict__ feat,
                                              unsigned short* __restrict__ F) {
    const int tid = threadIdx.x;
    const int wv = tid >> 6, l = tid & 63;
    const int g = l >> 3, j = l & 7;
    const int row = blockIdx.x * 32 + wv * 8 + g;
    const int b = row & (BSZ - 1), v = row >> 12;
    const float4* src = reinterpret_cast<const float4*>(feat + (size_t)(b * 2 + v) * DIM) + j * 4;
    const float4 x0 = src[0], x1 = src[1], x2 = src[2], x3 = src[3];
    float s = x0.x*x0.x + x0.y*x0.y + x0.z*x0.z + x0.w*x0.w
            + x1.x*x1.x + x1.y*x1.y + x1.z*x1.z + x1.w*x1.w
            + x2.x*x2.x + x2.y*x2.y + x2.z*x2.z + x2.w*x2.w
            + x3.x*x3.x + x3.y*x3.y + x3.z*x3.z + x3.w*x3.w;
    s += __shfl_xor(s, 1); s += __shfl_xor(s, 2); s += __shfl_xor(s, 4);
    const float inv = 1.0f / sqrtf(s + 1e-12f);
    uint4 w0, w1;
    w0.x = pack2(x0.x*inv, x0.y*inv); w0.y = pack2(x0.z*inv, x0.w*inv);
    w0.z = pack2(x1.x*inv, x1.y*inv); w0.w = pack2(x1.z*inv, x1.w*inv);
    w1.x = pack2(x2.x*inv, x2.y*inv); w1.y = pack2(x2.z*inv, x2.w*inv);
    w1.z = pack2(x3.x*inv, x3.y*inv); w1.w = pack2(x3.z*inv, x3.w*inv);
    uint4* dst = reinterpret_cast<uint4*>(F + (size_t)row * DIM);
    dst[j * 2]     = w0;
    dst[j * 2 + 1] = w1;
}

// ---------- kernel B: h[m][d] = sum_k a_k l_k^m F[k][d];  svec[m] = sum_k a_k l_k^m ----------
// grid 128 blocks x 128 thr; thread = d, block handles 64 k's. Atomic-accumulate.
__global__ __launch_bounds__(128) void hsum_k(const unsigned short* __restrict__ F,
                                              const float* __restrict__ labels,
                                              float* __restrict__ h, float* __restrict__ svec) {
    const int t = threadIdx.x;             // d = 0..127
    const int k0 = blockIdx.x * 64;
    float acc[10];
#pragma unroll
    for (int m = 0; m < 10; ++m) acc[m] = 0.f;
    float sv = 0.f;
    for (int kk = 0; kk < 64; ++kk) {
        const int k = k0 + kk;
        const float li = labels[k & (BSZ - 1)];
        const float a = __builtin_amdgcn_exp2f(li * li * C3);
        const float f = bf2f(F[(size_t)k * DIM + t]);
        float pm = a;
#pragma unroll
        for (int m = 0; m < 10; ++m) {
            acc[m] = fmaf(pm, f, acc[m]);
            if (t == m) sv += pm;
            pm *= li;
        }
    }
#pragma unroll
    for (int m = 0; m < 10; ++m) atomicAdd(&h[m * DIM + t], acc[m]);
    if (t < 10) atomicAdd(&svec[t], sv);
}

// ---------- kernel C: MFMA pairwise sweep, den only ----------
// 128-row stripes, wave owns 128 rows x 256 cols. grid 512 x 256thr (2 blocks/CU).
__global__ __launch_bounds__(256, 2) void supcon_mfma(
    const unsigned short* __restrict__ F, float* __restrict__ den_g)
{
    const int tid    = threadIdx.x;
    const int wv     = tid >> 6;
    const int l      = tid & 63;
    const int stripe = blockIdx.x >> 3;        // 0..63
    const int quad   = blockIdx.x & 7;         // 0..7
    const int chunk  = quad * 4 + wv;          // 0..31
    const int row0   = stripe * 128;
    const int colbeg = chunk * 256;
    const int l15 = l & 15, lh = l >> 4;

    // A fragments: row = row0 + set*16 + (l&15), k = kc*32 + (l>>4)*8 + j
    short8 a[8][4];
#pragma unroll
    for (int set = 0; set < 8; ++set) {
        const unsigned short* rp = F + (size_t)(row0 + set * 16 + l15) * DIM + lh * 8;
#pragma unroll
        for (int kc = 0; kc < 4; ++kc)
            a[set][kc] = *reinterpret_cast<const short8*>(rp + kc * 32);
    }

    float den[32];
#pragma unroll
    for (int p = 0; p < 32; ++p) den[p] = 0.f;

    for (int cb = 0; cb < 16; ++cb) {          // 16 col-blocks of 16
        const int col0 = colbeg + cb * 16;
        const unsigned short* cp = F + (size_t)(col0 + l15) * DIM + lh * 8;
        short8 bfr[4];
#pragma unroll
        for (int kc = 0; kc < 4; ++kc)
            bfr[kc] = *reinterpret_cast<const short8*>(cp + kc * 32);

#pragma unroll
        for (int set = 0; set < 8; ++set) {
            float4v acc = {0.f, 0.f, 0.f, 0.f};
#pragma unroll
            for (int kc = 0; kc < 4; ++kc)
                acc = __builtin_amdgcn_mfma_f32_16x16x32_bf16(a[set][kc], bfr[kc], acc, 0, 0, 0);
            const bool dtile = (col0 == row0 + set * 16);   // wave-uniform
#pragma unroll
            for (int r = 0; r < 4; ++r) {
                float e = __builtin_amdgcn_exp2f(__builtin_fmaf(acc[r], K1, -K1));
                if (dtile && (l15 == lh * 4 + r)) e = 0.f;  // i == k
                den[set * 4 + r] += e;
            }
        }
    }

    // reduce over the 16 lanes holding each row's columns
#pragma unroll
    for (int p = 0; p < 32; ++p) {
        den[p] += __shfl_xor(den[p], 1);
        den[p] += __shfl_xor(den[p], 2);
        den[p] += __shfl_xor(den[p], 4);
        den[p] += __shfl_xor(den[p], 8);
    }
    if (l15 == 0) {
#pragma unroll
        for (int set = 0; set < 8; ++set)
#pragma unroll
            for (int r = 0; r < 4; ++r)
                atomicAdd(&den_g[row0 + set * 16 + lh * 4 + r], den[set * 4 + r]);
    }
}

// ---------- kernel D: per-row loss + mean, fused ----------
// 8 lanes per row; swc_i = f_i . (sum_m c_m psi_m h_m); sw_i = sum_m c_m psi_m svec_m.
__global__ __launch_bounds__(256) void final_k(const float* __restrict__ feat,
    const float* __restrict__ labels, const float* __restrict__ den_g,
    const float* __restrict__ h, const float* __restrict__ svec,
    float* __restrict__ out)
{
    __shared__ float hs[10 * DIM];
    __shared__ float svs[10];
    const int tid = threadIdx.x;
    for (int i = tid; i < 10 * DIM; i += 256) hs[i] = h[i];
    if (tid < 10) svs[tid] = svec[tid];
    __syncthreads();

    const int wv = tid >> 6, l = tid & 63;
    const int g = l >> 3, j = l & 7;
    const int row = blockIdx.x * 32 + wv * 8 + g;
    const int b = row & (BSZ - 1), v = row >> 12;
    const float4* src = reinterpret_cast<const float4*>(feat + (size_t)(b * 2 + v) * DIM) + j * 4;
    const float4 x0 = src[0], x1 = src[1], x2 = src[2], x3 = src[3];
    float s = x0.x*x0.x + x0.y*x0.y + x0.z*x0.z + x0.w*x0.w
            + x1.x*x1.x + x1.y*x1.y + x1.z*x1.z + x1.w*x1.w
            + x2.x*x2.x + x2.y*x2.y + x2.z*x2.z + x2.w*x2.w
            + x3.x*x3.x + x3.y*x3.y + x3.z*x3.z + x3.w*x3.w;
    s += __shfl_xor(s, 1); s += __shfl_xor(s, 2); s += __shfl_xor(s, 4);
    const float inv = 1.0f / sqrtf(s + 1e-12f);

    const float li = labels[b];
    const float ai = __builtin_amdgcn_exp2f(li * li * C3);
    const float cf[10] = {1.f, 1.f, 0.5f, 1.f/6.f, 1.f/24.f, 1.f/120.f,
                          1.f/720.f, 1.f/5040.f, 1.f/40320.f, 1.f/362880.f};
    float swc = 0.f, sw = 0.f, pm = ai;
    const float* hb = &hs[j * 16];
#pragma unroll
    for (int m = 0; m < 10; ++m) {
        const float* hm = hb + m * DIM;
        const float d = x0.x*hm[0]  + x0.y*hm[1]  + x0.z*hm[2]  + x0.w*hm[3]
                      + x1.x*hm[4]  + x1.y*hm[5]  + x1.z*hm[6]  + x1.w*hm[7]
                      + x2.x*hm[8]  + x2.y*hm[9]  + x2.z*hm[10] + x2.w*hm[11]
                      + x3.x*hm[12] + x3.y*hm[13] + x3.z*hm[14] + x3.w*hm[15];
        const float cpm = cf[m] * pm;
        swc = fmaf(cpm, d, swc);
        sw  = fmaf(cpm, svs[m], sw);
        pm *= li;
    }
    swc += __shfl_xor(swc, 1); swc += __shfl_xor(swc, 2); swc += __shfl_xor(swc, 4);
    swc *= inv;   // f = x * inv

    const float den  = den_g[row];
    const float logd = logf(den + 1e-8f);
    const float loss = -(INV_T * swc - (M0 + logd) * sw) / fmaxf(sw, 1e-8f);

    // all 8 lanes of a row-group hold identical loss; wave-sum then scale by 1/8
    float part = loss * 0.125f;
    part += __shfl_xor(part, 1);  part += __shfl_xor(part, 2);  part += __shfl_xor(part, 4);
    part += __shfl_xor(part, 8);  part += __shfl_xor(part, 16); part += __shfl_xor(part, 32);
    if (l == 0) atomicAdd(out, part * (1.0f / NTOT));
}

extern "C" void kernel_launch(void* const* d_in, const int* in_sizes, int n_in,
                              void* d_out, int out_size, void* d_ws, size_t ws_size,
                              hipStream_t stream) {
    const float* feat   = (const float*)d_in[0];   // (4096, 2, 128) fp32
    const float* labels = (const float*)d_in[1];   // (4096,) fp32

    char* ws = (char*)d_ws;
    unsigned short* F = (unsigned short*)ws;                 // 2 MB bf16 normalized
    float* den_g = (float*)(ws + (size_t)NTOT * DIM * 2);    // 8192 f32
    float* h     = den_g + NTOT;                             // 10*128 f32
    float* svec  = h + 10 * DIM;                             // 10 f32 (pad 16)
    float* out   = (float*)d_out;

    hipMemsetAsync(den_g, 0, (NTOT + 10 * DIM + 16) * sizeof(float), stream);
    hipMemsetAsync(out, 0, sizeof(float), stream);
    norm_k<<<256, 256, 0, stream>>>(feat, F);
    hsum_k<<<128, 128, 0, stream>>>(F, labels, h, svec);
    supcon_mfma<<<512, 256, 0, stream>>>(F, den_g);
    final_k<<<256, 256, 0, stream>>>(feat, labels, den_g, h, svec, out);
}